// Round 5
// baseline (279.973 us; speedup 1.0000x reference)
//
#include <hip/hip_runtime.h>
#include <hip/hip_bf16.h>
#include <math.h>

#define B_  2
#define S_  2048
#define D_  1024
#define H_  16
#define DK_ 64

typedef __attribute__((ext_vector_type(8))) short bf16x8;   // 8 bf16 = 4 VGPRs
typedef __attribute__((ext_vector_type(4))) float f32x4;

#define MFMA_BF16(a, b, c) __builtin_amdgcn_mfma_f32_16x16x32_bf16((a), (b), (c), 0, 0, 0)

// 0.125 (1/sqrt(DK)) * log2(e): folded into Q so P = v_exp(S^T) directly
#define QSCALE 0.18033688011112042f
// log2(500000)/32 for RoPE inv_freq = 2^(-j * this)
#define ROPE_L2 0.591611512f

// fp32 -> bf16 round-to-nearest-even
__device__ __forceinline__ unsigned short f2bf(float f) {
  unsigned int u = __float_as_uint(f);
  u += 0x7FFFu + ((u >> 16) & 1u);
  return (unsigned short)(u >> 16);
}

// async global->LDS, 16 B per lane; LDS dest = wave-uniform base + lane*16
__device__ __forceinline__ void gl_lds16(const void* g, void* l) {
  __builtin_amdgcn_global_load_lds(
      (const __attribute__((address_space(1))) void*)g,
      (__attribute__((address_space(3))) void*)l, 16, 0, 0);
}

// XOR-swizzled LDS index (ushort units), rows = 64 ushorts = 8 16B chunks.
__device__ __forceinline__ int lsw(int row, int col) {
  return row * 64 + ((((col) >> 3) ^ (row & 7)) << 3) + (col & 7);
}

// ---------------------------------------------------------------------------
// fp32 -> bf16 conversion for q,k,v and the four weight matrices.
// ---------------------------------------------------------------------------
__global__ __launch_bounds__(256)
void cvt_bf16(const float* __restrict__ q, const float* __restrict__ k,
              const float* __restrict__ v, const float* __restrict__ wq,
              const float* __restrict__ wk, const float* __restrict__ wv,
              const float* __restrict__ wo,
              unsigned short* __restrict__ qb, unsigned short* __restrict__ kb,
              unsigned short* __restrict__ vb, unsigned short* __restrict__ wqb,
              unsigned short* __restrict__ wkb, unsigned short* __restrict__ wvb,
              unsigned short* __restrict__ wob) {
  const float* src; unsigned short* dst; int n;
  switch (blockIdx.y) {
    case 0: src = q;  dst = qb;  n = B_ * S_ * D_; break;
    case 1: src = k;  dst = kb;  n = B_ * S_ * D_; break;
    case 2: src = v;  dst = vb;  n = B_ * S_ * D_; break;
    case 3: src = wq; dst = wqb; n = D_ * D_; break;
    case 4: src = wk; dst = wkb; n = D_ * D_; break;
    case 5: src = wv; dst = wvb; n = D_ * D_; break;
    default: src = wo; dst = wob; n = D_ * D_; break;
  }
  const int i = (blockIdx.x * 256 + threadIdx.x) * 4;
  if (i >= n) return;
  float4 val = *(const float4*)&src[i];
  ushort4 r4;
  r4.x = f2bf(val.x); r4.y = f2bf(val.y); r4.z = f2bf(val.z); r4.w = f2bf(val.w);
  *(ushort4*)&dst[i] = r4;
}

// ---------------------------------------------------------------------------
// Direct-register QKV projection GEMM: NO LDS, NO barriers. Fragments are
// loaded straight from global (16 B/lane coalesced) with ping-pong register
// double-buffering; waves run independently, latency hidden by 12 waves/CU +
// depth-1 prefetch + fine-grained compiler vmcnt. Operands are L2-resident
// per XCD by the 1-D grid decode: y = b&31, x = (b>>5)&7, z = b>>8 ->
// A-panel sharers differ by 32 blocks = same XCD (32 % 8 == 0); W = 2 MB
// caches per XCD (per-XCD set: 4 A-panels (1 MB) + W (2 MB) < 4 MB L2).
// Epilogues (per z): 0 = RMSNorm+RoPE+QSCALE -> Q, 1 = RMSNorm+RoPE -> K,
// 2 = V transposed [b][h][dk][s].
// ---------------------------------------------------------------------------
__global__ __launch_bounds__(256, 3)
void gemm_qkv(const unsigned short* __restrict__ qa, const unsigned short* __restrict__ ka,
              const unsigned short* __restrict__ va,
              const unsigned short* __restrict__ wq, const unsigned short* __restrict__ wk,
              const unsigned short* __restrict__ wv,
              unsigned short* __restrict__ Qo, unsigned short* __restrict__ Ko,
              unsigned short* __restrict__ Vto,
              const float* __restrict__ qnw, const float* __restrict__ knw) {
  const int bidx = blockIdx.x;
  const int by = bidx & 31;          // m-panel
  const int bxj = (bidx >> 5) & 7;   // j-panel
  const int z = bidx >> 8;           // 0=Q 1=K 2=V
  const unsigned short* A = (z == 0) ? qa : (z == 1) ? ka : va;
  const unsigned short* W = (z == 0) ? wq : (z == 1) ? wk : wv;

  const int t = threadIdx.x, lane = t & 63, wave = t >> 6;
  const int l16 = lane & 15, quad = lane >> 4;
  const int wm = wave >> 1, wn = wave & 1;
  const int m0 = by * 128, j0 = bxj * 128;

  f32x4 acc[4][4];
#pragma unroll
  for (int i = 0; i < 4; ++i)
#pragma unroll
    for (int j = 0; j < 4; ++j) acc[i][j] = (f32x4)(0.0f);

  // A-frag: row = m0 + wm*64 + mi*16 + l16, k = kb + quad*8  (16 B / lane)
  const unsigned short* Arow = A + (size_t)(m0 + wm * 64 + l16) * D_ + quad * 8;
  const unsigned short* Wrow = W + (size_t)(j0 + wn * 64 + l16) * D_ + quad * 8;

  bf16x8 a0[4], b0[4], a1[4], b1[4];
  auto loadf = [&](bf16x8* af, bf16x8* bf, int kb) {
#pragma unroll
    for (int i = 0; i < 4; ++i) {
      af[i] = *(const bf16x8*)(Arow + (size_t)i * 16 * D_ + kb);
      bf[i] = *(const bf16x8*)(Wrow + (size_t)i * 16 * D_ + kb);
    }
  };
  auto comp = [&](bf16x8* af, bf16x8* bf) {
#pragma unroll
    for (int mi = 0; mi < 4; ++mi)
#pragma unroll
      for (int ni = 0; ni < 4; ++ni)
        acc[mi][ni] = MFMA_BF16(af[mi], bf[ni], acc[mi][ni]);
  };

  loadf(a0, b0, 0);
  for (int kb = 0; kb < D_; kb += 64) {
    if (kb + 32 < D_) loadf(a1, b1, kb + 32);
    comp(a0, b0);
    if (kb + 64 < D_) loadf(a0, b0, kb + 64);
    comp(a1, b1);
  }

  // epilogue. C/D layout: col = l16 (n), row = quad*4 + reg (m).
  const int h = bxj * 2 + wn;   // one head per 64-col wave-half
  if (z == 2) {
    // V^T: [b][h][dk][s], packed 4-bf16 (8B) stores along s
#pragma unroll
    for (int mi = 0; mi < 4; ++mi) {
      const int rowb = m0 + wm * 64 + mi * 16 + quad * 4;
      const int b = rowb >> 11, s0 = rowb & (S_ - 1);
#pragma unroll
      for (int ni = 0; ni < 4; ++ni) {
        const int dk = ni * 16 + l16;
        const unsigned int u0 =
            (unsigned int)f2bf(acc[mi][ni][0]) | ((unsigned int)f2bf(acc[mi][ni][1]) << 16);
        const unsigned int u1 =
            (unsigned int)f2bf(acc[mi][ni][2]) | ((unsigned int)f2bf(acc[mi][ni][3]) << 16);
        *(uint2*)&Vto[((size_t)((b * H_ + h) * DK_ + dk)) * S_ + s0] = make_uint2(u0, u1);
      }
    }
  } else {
    unsigned short* out = (z == 0) ? Qo : Ko;
    const float* nw = (z == 0) ? qnw : knw;
    const float sc  = (z == 0) ? QSCALE : 1.0f;
    float wv_[4];
#pragma unroll
    for (int ni = 0; ni < 4; ++ni) wv_[ni] = nw[ni * 16 + l16];
    const float invA = exp2f(-(float)l16 * ROPE_L2);         // j = l16
    const float invB = exp2f(-(float)(16 + l16) * ROPE_L2);  // j = 16 + l16
#pragma unroll
    for (int mi = 0; mi < 4; ++mi) {
#pragma unroll
      for (int r = 0; r < 4; ++r) {
        const int rowg = m0 + wm * 64 + mi * 16 + quad * 4 + r;
        const int b = rowg >> 11, s = rowg & (S_ - 1);
        float ss = 0.f;
#pragma unroll
        for (int ni = 0; ni < 4; ++ni) ss += acc[mi][ni][r] * acc[mi][ni][r];
#pragma unroll
        for (int m = 1; m < 16; m <<= 1) ss += __shfl_xor(ss, m);
        const float rms = rsqrtf(ss * (1.0f / DK_) + 1e-10f);
        float xn[4];
#pragma unroll
        for (int ni = 0; ni < 4; ++ni) xn[ni] = wv_[ni] * acc[mi][ni][r] * rms;
        const float fA = (float)s * invA, fB = (float)s * invB;
        const float cA = __cosf(fA) * sc, sA = __sinf(fA) * sc;
        const float cB = __cosf(fB) * sc, sB = __sinf(fB) * sc;
        float o0 = xn[0] * cA - xn[2] * sA;   // dk = l16       (<32, j=A)
        float o1 = xn[1] * cB - xn[3] * sB;   // dk = 16+l16    (<32, j=B)
        float o2 = xn[2] * cA + xn[0] * sA;   // dk = 32+l16    (>=32, j=A)
        float o3 = xn[3] * cB + xn[1] * sB;   // dk = 48+l16    (>=32, j=B)
        const size_t base = ((size_t)(b * H_ + h) * S_ + s) * DK_;
        out[base +  0 + l16] = f2bf(o0);
        out[base + 16 + l16] = f2bf(o1);
        out[base + 32 + l16] = f2bf(o2);
        out[base + 48 + l16] = f2bf(o3);
      }
    }
  }
}

// ---------------------------------------------------------------------------
// Flash attention v3 (unchanged from R4): 64-row Q-tiles, grid 1024 = 4
// blocks/CU (LDS 40KB x 4 = 160 KiB), qt fold for uniform causal work,
// S^T = K Q^T, no-max softmax, l via ones-MFMA, single barrier per tile,
// double-buffered gl_lds16 staging, XOR-swizzled LDS, wave-private P.
// ---------------------------------------------------------------------------
__global__ __launch_bounds__(256)
void flash3(const unsigned short* __restrict__ Q, const unsigned short* __restrict__ K,
            const unsigned short* __restrict__ Vt, unsigned short* __restrict__ Oa) {
  __shared__ unsigned short Ks[2][64 * 64];
  __shared__ unsigned short Vs[2][64 * 64];
  __shared__ unsigned short Ps[64 * 64];
  const int bx = blockIdx.x;
  const int idx = bx >> 5;
  const int qt = (idx < 16) ? idx : (47 - idx);   // balance across co-residents
  const int bh = bx & 31;
  const int t = threadIdx.x, lane = t & 63, wave = t >> 6;
  const int l16 = lane & 15, quad = lane >> 4;
  const size_t hb = (size_t)bh * S_ * DK_;
  const unsigned short* Qh  = Q + hb;
  const unsigned short* Kh  = K + hb;
  const unsigned short* Vth = Vt + hb;      // [dk][s]

  bf16x8 qf[2];
#pragma unroll
  for (int ks = 0; ks < 2; ++ks)
    qf[ks] = *(const bf16x8*)
      &Qh[(size_t)(qt * 64 + wave * 16 + l16) * DK_ + ks * 32 + quad * 8];

  bf16x8 ones;
#pragma unroll
  for (int j = 0; j < 8; ++j) ones[j] = (short)0x3F80;  // bf16 1.0

  f32x4 o[4], lacc;
  lacc = (f32x4)(0.0f);
#pragma unroll
  for (int ni = 0; ni < 4; ++ni) o[ni] = (f32x4)(0.0f);

  auto stage = [&](int kt, int bufi) {
#pragma unroll
    for (int i = 0; i < 2; ++i) {
      const int rbase = wave * 16 + i * 8;
      const int r = rbase + (lane >> 3);
      const int c = ((lane & 7) ^ (r & 7)) * 8;   // logical col (ushorts)
      gl_lds16(&Kh[(size_t)(kt * 64 + r) * DK_ + c], &Ks[bufi][rbase * 64]);
      gl_lds16(&Vth[(size_t)r * S_ + kt * 64 + c], &Vs[bufi][rbase * 64]);
    }
  };

  const int nkt = qt + 1;
  stage(0, 0);
  for (int kt = 0; kt < nkt; ++kt) {
    const int buf = kt & 1;
    __syncthreads();          // drains vmcnt: staged buf ready; buf^1 free
    if (kt + 1 < nkt) stage(kt + 1, buf ^ 1);

    f32x4 sv[4];
#pragma unroll
    for (int kvi = 0; kvi < 4; ++kvi) sv[kvi] = (f32x4)(0.0f);
#pragma unroll
    for (int ks = 0; ks < 2; ++ks) {
      bf16x8 ak[4];
#pragma unroll
      for (int kvi = 0; kvi < 4; ++kvi)
        ak[kvi] = *(const bf16x8*)&Ks[buf][lsw(kvi * 16 + l16, ks * 32 + quad * 8)];
#pragma unroll
      for (int kvi = 0; kvi < 4; ++kvi)
        sv[kvi] = MFMA_BF16(ak[kvi], qf[ks], sv[kvi]);
    }

    float p[4][4];
    if (kt == qt) {
      const int qg = qt * 64 + wave * 16 + l16;
#pragma unroll
      for (int kvi = 0; kvi < 4; ++kvi)
#pragma unroll
        for (int r = 0; r < 4; ++r) {
          float x = sv[kvi][r];
          if ((kt * 64 + kvi * 16 + quad * 4 + r) > qg) x = -INFINITY;
          p[kvi][r] = exp2f(x);
        }
    } else {
#pragma unroll
      for (int kvi = 0; kvi < 4; ++kvi)
#pragma unroll
        for (int r = 0; r < 4; ++r) p[kvi][r] = exp2f(sv[kvi][r]);
    }

#pragma unroll
    for (int kvi = 0; kvi < 4; ++kvi) {
      const unsigned int d0 =
          (__float_as_uint(p[kvi][1]) & 0xFFFF0000u) | (__float_as_uint(p[kvi][0]) >> 16);
      const unsigned int d1 =
          (__float_as_uint(p[kvi][3]) & 0xFFFF0000u) | (__float_as_uint(p[kvi][2]) >> 16);
      *(uint2*)&Ps[lsw(wave * 16 + l16, kvi * 16 + quad * 4)] = make_uint2(d0, d1);
    }
    asm volatile("s_waitcnt lgkmcnt(0)" ::: "memory");  // P visible to own wave

#pragma unroll
    for (int ks = 0; ks < 2; ++ks) {
      bf16x8 ap, bv[4];
      ap = *(const bf16x8*)&Ps[lsw(wave * 16 + l16, ks * 32 + quad * 8)];
#pragma unroll
      for (int ni = 0; ni < 4; ++ni)
        bv[ni] = *(const bf16x8*)&Vs[buf][lsw(ni * 16 + l16, ks * 32 + quad * 8)];
#pragma unroll
      for (int ni = 0; ni < 4; ++ni)
        o[ni] = MFMA_BF16(ap, bv[ni], o[ni]);
      lacc = MFMA_BF16(ap, ones, lacc);
    }
  }

  const int b = bh >> 4, h = bh & 15;
#pragma unroll
  for (int r = 0; r < 4; ++r) {
    const int srow = qt * 64 + wave * 16 + quad * 4 + r;
    const float linv = 1.0f / lacc[r];
#pragma unroll
    for (int ni = 0; ni < 4; ++ni)
      Oa[((size_t)(b * S_ + srow) * H_ + h) * DK_ + ni * 16 + l16] =
          f2bf(o[ni][r] * linv);
  }
}

// ---------------------------------------------------------------------------
// Final output GEMM, direct-register (no LDS / no barriers, same as gemm_qkv):
// fp32 row-major C = A(bf16) @ Wo(bf16)^T
// ---------------------------------------------------------------------------
__global__ __launch_bounds__(256, 3)
void gemm_out(const unsigned short* __restrict__ A, const unsigned short* __restrict__ W,
              float* __restrict__ out) {
  const int bidx = blockIdx.x;
  const int by = bidx & 31;        // m-panel
  const int bxj = bidx >> 5;       // j-panel (8)
  const int t = threadIdx.x, lane = t & 63, wave = t >> 6;
  const int l16 = lane & 15, quad = lane >> 4;
  const int wm = wave >> 1, wn = wave & 1;
  const int m0 = by * 128, j0 = bxj * 128;

  f32x4 acc[4][4];
#pragma unroll
  for (int i = 0; i < 4; ++i)
#pragma unroll
    for (int j = 0; j < 4; ++j) acc[i][j] = (f32x4)(0.0f);

  const unsigned short* Arow = A + (size_t)(m0 + wm * 64 + l16) * D_ + quad * 8;
  const unsigned short* Wrow = W + (size_t)(j0 + wn * 64 + l16) * D_ + quad * 8;

  bf16x8 a0[4], b0[4], a1[4], b1[4];
  auto loadf = [&](bf16x8* af, bf16x8* bf, int kb) {
#pragma unroll
    for (int i = 0; i < 4; ++i) {
      af[i] = *(const bf16x8*)(Arow + (size_t)i * 16 * D_ + kb);
      bf[i] = *(const bf16x8*)(Wrow + (size_t)i * 16 * D_ + kb);
    }
  };
  auto comp = [&](bf16x8* af, bf16x8* bf) {
#pragma unroll
    for (int mi = 0; mi < 4; ++mi)
#pragma unroll
      for (int ni = 0; ni < 4; ++ni)
        acc[mi][ni] = MFMA_BF16(af[mi], bf[ni], acc[mi][ni]);
  };

  loadf(a0, b0, 0);
  for (int kb = 0; kb < D_; kb += 64) {
    if (kb + 32 < D_) loadf(a1, b1, kb + 32);
    comp(a0, b0);
    if (kb + 64 < D_) loadf(a0, b0, kb + 64);
    comp(a1, b1);
  }

#pragma unroll
  for (int mi = 0; mi < 4; ++mi) {
    const int rowb = m0 + wm * 64 + mi * 16 + quad * 4;
#pragma unroll
    for (int ni = 0; ni < 4; ++ni) {
      const int col = j0 + wn * 64 + ni * 16 + l16;
#pragma unroll
      for (int r = 0; r < 4; ++r)
        out[(size_t)(rowb + r) * D_ + col] = acc[mi][ni][r];
    }
  }
}

// ---------------------------------------------------------------------------
extern "C" void kernel_launch(void* const* d_in, const int* in_sizes, int n_in,
                              void* d_out, int out_size, void* d_ws, size_t ws_size,
                              hipStream_t stream) {
  (void)in_sizes; (void)n_in; (void)out_size; (void)ws_size;
  const float* q  = (const float*)d_in[0];
  const float* k  = (const float*)d_in[1];
  const float* v  = (const float*)d_in[2];
  const float* Wq = (const float*)d_in[3];
  const float* Wk = (const float*)d_in[4];
  const float* Wv = (const float*)d_in[5];
  const float* Wo = (const float*)d_in[6];
  const float* qw = (const float*)d_in[7];
  const float* kw = (const float*)d_in[8];

  char* ws = (char*)d_ws;
  const size_t MB = 1u << 20;
  unsigned short* qb  = (unsigned short*)(ws + 0 * MB);    // bf16 inputs
  unsigned short* kb  = (unsigned short*)(ws + 8 * MB);
  unsigned short* vb  = (unsigned short*)(ws + 16 * MB);
  unsigned short* wqb = (unsigned short*)(ws + 24 * MB);
  unsigned short* wkb = (unsigned short*)(ws + 26 * MB);
  unsigned short* wvb = (unsigned short*)(ws + 28 * MB);
  unsigned short* wob = (unsigned short*)(ws + 30 * MB);
  unsigned short* Qb  = (unsigned short*)(ws + 32 * MB);   // normed+roped Q (scaled)
  unsigned short* Kb  = (unsigned short*)(ws + 40 * MB);   // normed+roped K
  unsigned short* Vtb = (unsigned short*)(ws + 48 * MB);   // V^T [bh][dk][s]
  unsigned short* Ab  = (unsigned short*)(ws + 56 * MB);   // attn out row-major

  cvt_bf16<<<dim3(4096, 7), 256, 0, stream>>>(q, k, v, Wq, Wk, Wv, Wo,
                                              qb, kb, vb, wqb, wkb, wvb, wob);

  gemm_qkv<<<768, 256, 0, stream>>>(qb, kb, vb, wqb, wkb, wvb, Qb, Kb, Vtb, qw, kw);

  flash3<<<1024, 256, 0, stream>>>(Qb, Kb, Vtb, Ab);

  gemm_out<<<256, 256, 0, stream>>>(Ab, wob, (float*)d_out);
}

// Round 6
// 218.477 us; speedup vs baseline: 1.2815x; 1.2815x over previous
//
#include <hip/hip_runtime.h>
#include <hip/hip_bf16.h>
#include <math.h>

#define B_  2
#define S_  2048
#define D_  1024
#define H_  16
#define DK_ 64

typedef __attribute__((ext_vector_type(8))) short bf16x8;   // 8 bf16 = 4 VGPRs
typedef __attribute__((ext_vector_type(4))) float f32x4;

#define MFMA_BF16(a, b, c) __builtin_amdgcn_mfma_f32_16x16x32_bf16((a), (b), (c), 0, 0, 0)

// 0.125 (1/sqrt(DK)) * log2(e): folded into Q so P = v_exp(S^T) directly
#define QSCALE 0.18033688011112042f
// log2(500000)/32 for RoPE inv_freq = 2^(-j * this)
#define ROPE_L2 0.591611512f

// fp32 -> bf16 round-to-nearest-even
__device__ __forceinline__ unsigned short f2bf(float f) {
  unsigned int u = __float_as_uint(f);
  u += 0x7FFFu + ((u >> 16) & 1u);
  return (unsigned short)(u >> 16);
}

// async global->LDS, 16 B per lane; LDS dest = wave-uniform base + lane*16
__device__ __forceinline__ void gl_lds16(const void* g, void* l) {
  __builtin_amdgcn_global_load_lds(
      (const __attribute__((address_space(1))) void*)g,
      (__attribute__((address_space(3))) void*)l, 16, 0, 0);
}

// XOR-swizzled LDS index (ushort units), rows = 64 ushorts = 8 16B chunks.
__device__ __forceinline__ int lsw(int row, int col) {
  return row * 64 + ((((col) >> 3) ^ (row & 7)) << 3) + (col & 7);
}

// ---------------------------------------------------------------------------
// fp32 -> bf16 conversion for q,k,v and the four weight matrices.
// ---------------------------------------------------------------------------
__global__ __launch_bounds__(256)
void cvt_bf16(const float* __restrict__ q, const float* __restrict__ k,
              const float* __restrict__ v, const float* __restrict__ wq,
              const float* __restrict__ wk, const float* __restrict__ wv,
              const float* __restrict__ wo,
              unsigned short* __restrict__ qb, unsigned short* __restrict__ kb,
              unsigned short* __restrict__ vb, unsigned short* __restrict__ wqb,
              unsigned short* __restrict__ wkb, unsigned short* __restrict__ wvb,
              unsigned short* __restrict__ wob) {
  const float* src; unsigned short* dst; int n;
  switch (blockIdx.y) {
    case 0: src = q;  dst = qb;  n = B_ * S_ * D_; break;
    case 1: src = k;  dst = kb;  n = B_ * S_ * D_; break;
    case 2: src = v;  dst = vb;  n = B_ * S_ * D_; break;
    case 3: src = wq; dst = wqb; n = D_ * D_; break;
    case 4: src = wk; dst = wkb; n = D_ * D_; break;
    case 5: src = wv; dst = wvb; n = D_ * D_; break;
    default: src = wo; dst = wob; n = D_ * D_; break;
  }
  const int i = (blockIdx.x * 256 + threadIdx.x) * 4;
  if (i >= n) return;
  float4 val = *(const float4*)&src[i];
  ushort4 r4;
  r4.x = f2bf(val.x); r4.y = f2bf(val.y); r4.z = f2bf(val.z); r4.w = f2bf(val.w);
  *(ushort4*)&dst[i] = r4;
}

// ---------------------------------------------------------------------------
// Fused QKV projection GEMM (R4 LDS form — R5's no-LDS variant was L2-latency
// bound at MfmaUtil 10%; reverted). 128x128 tile, BK=32, double-buffered
// global_load_lds staging. Epilogues: z=0 RMSNorm+RoPE+QSCALE -> Q head-major,
// z=1 RMSNorm+RoPE -> K head-major, z=2 V transposed [b][h][dk][s].
// ---------------------------------------------------------------------------
__global__ __launch_bounds__(256)
void gemm_qkv(const unsigned short* __restrict__ qa, const unsigned short* __restrict__ ka,
              const unsigned short* __restrict__ va,
              const unsigned short* __restrict__ wq, const unsigned short* __restrict__ wk,
              const unsigned short* __restrict__ wv,
              unsigned short* __restrict__ Qo, unsigned short* __restrict__ Ko,
              unsigned short* __restrict__ Vto,
              const float* __restrict__ qnw, const float* __restrict__ knw) {
  __shared__ unsigned short As[2][128 * 32];
  __shared__ unsigned short Bs[2][128 * 32];
  const int z = blockIdx.z;
  const unsigned short* A = (z == 0) ? qa : (z == 1) ? ka : va;
  const unsigned short* W = (z == 0) ? wq : (z == 1) ? wk : wv;

  const int t = threadIdx.x, lane = t & 63, wave = t >> 6;
  const int l16 = lane & 15, quad = lane >> 4;
  const int wm = wave >> 1, wn = wave & 1;
  const int m0 = blockIdx.y * 128, j0 = blockIdx.x * 128;

  f32x4 acc[4][4];
#pragma unroll
  for (int i = 0; i < 4; ++i)
#pragma unroll
    for (int j = 0; j < 4; ++j) acc[i][j] = (f32x4)(0.0f);

  auto stage = [&](int kb, int buf) {
#pragma unroll
    for (int i = 0; i < 2; ++i) {
      const int c  = (wave * 2 + i) * 64 + lane;  // 16B chunk id, 0..511
      const int r  = c >> 2;                      // tile row 0..127
      const int co = (c & 3) * 8;                 // ushort offset in 32-wide row
      gl_lds16(&A[(size_t)(m0 + r) * D_ + kb + co], &As[buf][(wave * 2 + i) * 512]);
      gl_lds16(&W[(size_t)(j0 + r) * D_ + kb + co], &Bs[buf][(wave * 2 + i) * 512]);
    }
  };

  stage(0, 0);
  for (int kb = 0; kb < D_; kb += 32) {
    const int buf = (kb >> 5) & 1;
    __syncthreads();                 // staged buf ready (vmcnt drained at barrier)
    if (kb + 32 < D_) stage(kb + 32, buf ^ 1);

    bf16x8 af[4], bfr[4];
#pragma unroll
    for (int mi = 0; mi < 4; ++mi)
      af[mi] = *(const bf16x8*)&As[buf][(wm * 64 + mi * 16 + l16) * 32 + quad * 8];
#pragma unroll
    for (int ni = 0; ni < 4; ++ni)
      bfr[ni] = *(const bf16x8*)&Bs[buf][(wn * 64 + ni * 16 + l16) * 32 + quad * 8];
#pragma unroll
    for (int mi = 0; mi < 4; ++mi)
#pragma unroll
      for (int ni = 0; ni < 4; ++ni)
        acc[mi][ni] = MFMA_BF16(af[mi], bfr[ni], acc[mi][ni]);
  }

  // epilogue. C/D layout: col = l16 (n), row = quad*4 + reg (m).
  const int h = blockIdx.x * 2 + wn;   // one head per 64-col wave-half
  if (z == 2) {
    // V^T: [b][h][dk][s], packed 4-bf16 (8B) stores along s
#pragma unroll
    for (int mi = 0; mi < 4; ++mi) {
      const int rowb = m0 + wm * 64 + mi * 16 + quad * 4;
      const int b = rowb >> 11, s0 = rowb & (S_ - 1);
#pragma unroll
      for (int ni = 0; ni < 4; ++ni) {
        const int dk = ni * 16 + l16;
        const unsigned int u0 =
            (unsigned int)f2bf(acc[mi][ni][0]) | ((unsigned int)f2bf(acc[mi][ni][1]) << 16);
        const unsigned int u1 =
            (unsigned int)f2bf(acc[mi][ni][2]) | ((unsigned int)f2bf(acc[mi][ni][3]) << 16);
        *(uint2*)&Vto[((size_t)((b * H_ + h) * DK_ + dk)) * S_ + s0] = make_uint2(u0, u1);
      }
    }
  } else {
    unsigned short* out = (z == 0) ? Qo : Ko;
    const float* nw = (z == 0) ? qnw : knw;
    const float sc  = (z == 0) ? QSCALE : 1.0f;
    float wv_[4];
#pragma unroll
    for (int ni = 0; ni < 4; ++ni) wv_[ni] = nw[ni * 16 + l16];
    const float invA = exp2f(-(float)l16 * ROPE_L2);         // j = l16
    const float invB = exp2f(-(float)(16 + l16) * ROPE_L2);  // j = 16 + l16
#pragma unroll
    for (int mi = 0; mi < 4; ++mi) {
#pragma unroll
      for (int r = 0; r < 4; ++r) {
        const int rowg = m0 + wm * 64 + mi * 16 + quad * 4 + r;
        const int b = rowg >> 11, s = rowg & (S_ - 1);
        float ss = 0.f;
#pragma unroll
        for (int ni = 0; ni < 4; ++ni) ss += acc[mi][ni][r] * acc[mi][ni][r];
#pragma unroll
        for (int m = 1; m < 16; m <<= 1) ss += __shfl_xor(ss, m);
        const float rms = rsqrtf(ss * (1.0f / DK_) + 1e-10f);
        float xn[4];
#pragma unroll
        for (int ni = 0; ni < 4; ++ni) xn[ni] = wv_[ni] * acc[mi][ni][r] * rms;
        const float fA = (float)s * invA, fB = (float)s * invB;
        const float cA = __cosf(fA) * sc, sA = __sinf(fA) * sc;
        const float cB = __cosf(fB) * sc, sB = __sinf(fB) * sc;
        float o0 = xn[0] * cA - xn[2] * sA;   // dk = l16       (<32, j=A)
        float o1 = xn[1] * cB - xn[3] * sB;   // dk = 16+l16    (<32, j=B)
        float o2 = xn[2] * cA + xn[0] * sA;   // dk = 32+l16    (>=32, j=A)
        float o3 = xn[3] * cB + xn[1] * sB;   // dk = 48+l16    (>=32, j=B)
        const size_t base = ((size_t)(b * H_ + h) * S_ + s) * DK_;
        out[base +  0 + l16] = f2bf(o0);
        out[base + 16 + l16] = f2bf(o1);
        out[base + 32 + l16] = f2bf(o2);
        out[base + 48 + l16] = f2bf(o3);
      }
    }
  }
}

// ---------------------------------------------------------------------------
// Flash attention v4. vs v3: S^T computed with per-wave kv-ownership —
// wave w owns kv rows w*16..+15 and ALL 64 q columns (Q fragments for all 4
// q-tiles live in registers), so K-fragment LDS reads drop 8 -> 2 per wave
// per tile (v3 had all 4 waves redundantly reading identical K frags).
// P then crosses waves, so a lgkm-ONLY raw s_barrier (not __syncthreads —
// that would vmcnt-drain the in-flight K/V prefetch) separates P-write from
// the PV read. LDS reads/wave/tile: 18 -> 12. Grid 1024 = 4 blocks/CU,
// qt fold for uniform causal work per CU.
// ---------------------------------------------------------------------------
__global__ __launch_bounds__(256, 4)
void flash4(const unsigned short* __restrict__ Q, const unsigned short* __restrict__ K,
            const unsigned short* __restrict__ Vt, unsigned short* __restrict__ Oa) {
  __shared__ unsigned short Ks[2][64 * 64];
  __shared__ unsigned short Vs[2][64 * 64];
  __shared__ unsigned short Ps[64 * 64];
  const int bx = blockIdx.x;
  const int idx = bx >> 5;
  const int qt = (idx < 16) ? idx : (47 - idx);   // balance across co-residents
  const int bh = bx & 31;
  const int t = threadIdx.x, lane = t & 63, wave = t >> 6;
  const int l16 = lane & 15, quad = lane >> 4;
  const size_t hb = (size_t)bh * S_ * DK_;
  const unsigned short* Qh  = Q + hb;
  const unsigned short* Kh  = K + hb;
  const unsigned short* Vth = Vt + hb;      // [dk][s]

  // All 64 Q rows as B-fragments: qf[ni][ks], n = q = qt*64 + ni*16 + l16,
  // k = dk = ks*32 + quad*8.. (pre-scaled by QSCALE*log2e at projection)
  bf16x8 qf[4][2];
#pragma unroll
  for (int ni = 0; ni < 4; ++ni)
#pragma unroll
    for (int ks = 0; ks < 2; ++ks)
      qf[ni][ks] = *(const bf16x8*)
        &Qh[(size_t)(qt * 64 + ni * 16 + l16) * DK_ + ks * 32 + quad * 8];

  bf16x8 ones;
#pragma unroll
  for (int j = 0; j < 8; ++j) ones[j] = (short)0x3F80;  // bf16 1.0

  f32x4 o[4], lacc;
  lacc = (f32x4)(0.0f);
#pragma unroll
  for (int ni = 0; ni < 4; ++ni) o[ni] = (f32x4)(0.0f);

  auto stage = [&](int kt, int bufi) {
#pragma unroll
    for (int i = 0; i < 2; ++i) {
      const int rbase = wave * 16 + i * 8;
      const int r = rbase + (lane >> 3);
      const int c = ((lane & 7) ^ (r & 7)) * 8;   // logical col (ushorts)
      gl_lds16(&Kh[(size_t)(kt * 64 + r) * DK_ + c], &Ks[bufi][rbase * 64]);
      gl_lds16(&Vth[(size_t)r * S_ + kt * 64 + c], &Vs[bufi][rbase * 64]);
    }
  };

  const int nkt = qt + 1;
  stage(0, 0);
  for (int kt = 0; kt < nkt; ++kt) {
    const int buf = kt & 1;
    __syncthreads();          // drains vmcnt: staged buf ready; buf^1 free
    if (kt + 1 < nkt) stage(kt + 1, buf ^ 1);

    // S^T: wave owns kv rows wave*16..+15; A = K-frag (2 reads), B = qf regs.
    f32x4 sv[4];
#pragma unroll
    for (int ni = 0; ni < 4; ++ni) sv[ni] = (f32x4)(0.0f);
#pragma unroll
    for (int ks = 0; ks < 2; ++ks) {
      const bf16x8 ak = *(const bf16x8*)&Ks[buf][lsw(wave * 16 + l16, ks * 32 + quad * 8)];
#pragma unroll
      for (int ni = 0; ni < 4; ++ni)
        sv[ni] = MFMA_BF16(ak, qf[ni][ks], sv[ni]);
    }

    // exp2 (+ mask only on the diagonal tile). C-layout of sv[ni]:
    // q = qt*64 + ni*16 + l16 (col), kv = kt*64 + wave*16 + quad*4 + r (row).
    float p[4][4];
    if (kt == qt) {
      const int kvb = kt * 64 + wave * 16 + quad * 4;
#pragma unroll
      for (int ni = 0; ni < 4; ++ni) {
        const int qg = qt * 64 + ni * 16 + l16;
#pragma unroll
        for (int r = 0; r < 4; ++r) {
          float x = sv[ni][r];
          if ((kvb + r) > qg) x = -INFINITY;
          p[ni][r] = exp2f(x);
        }
      }
    } else {
#pragma unroll
      for (int ni = 0; ni < 4; ++ni)
#pragma unroll
        for (int r = 0; r < 4; ++r) p[ni][r] = exp2f(sv[ni][r]);
    }

    // P[q][kv] bf16: row = q = ni*16+l16, col = kv = wave*16+quad*4 (+0..3)
#pragma unroll
    for (int ni = 0; ni < 4; ++ni) {
      const unsigned int d0 =
          (__float_as_uint(p[ni][1]) & 0xFFFF0000u) | (__float_as_uint(p[ni][0]) >> 16);
      const unsigned int d1 =
          (__float_as_uint(p[ni][3]) & 0xFFFF0000u) | (__float_as_uint(p[ni][2]) >> 16);
      *(uint2*)&Ps[lsw(ni * 16 + l16, wave * 16 + quad * 4)] = make_uint2(d0, d1);
    }
    // Cross-wave P handoff: LDS-only barrier. NOT __syncthreads -- that emits
    // s_waitcnt vmcnt(0) and would drain the kt+1 staging prefetch.
    asm volatile("s_waitcnt lgkmcnt(0)\n\ts_barrier" ::: "memory");

    // O += P V, l += P 1. A = P[q = wave*16+l16][kv], B = V[kv][dk].
#pragma unroll
    for (int ks = 0; ks < 2; ++ks) {
      bf16x8 ap, bv[4];
      ap = *(const bf16x8*)&Ps[lsw(wave * 16 + l16, ks * 32 + quad * 8)];
#pragma unroll
      for (int ni = 0; ni < 4; ++ni)
        bv[ni] = *(const bf16x8*)&Vs[buf][lsw(ni * 16 + l16, ks * 32 + quad * 8)];
#pragma unroll
      for (int ni = 0; ni < 4; ++ni)
        o[ni] = MFMA_BF16(ap, bv[ni], o[ni]);
      lacc = MFMA_BF16(ap, ones, lacc);
    }
  }

  // epilogue: O /= l, write bf16 row-major attn [b*S+s][h*64+dk]
  const int b = bh >> 4, h = bh & 15;
#pragma unroll
  for (int r = 0; r < 4; ++r) {
    const int srow = qt * 64 + wave * 16 + quad * 4 + r;
    const float linv = 1.0f / lacc[r];
#pragma unroll
    for (int ni = 0; ni < 4; ++ni)
      Oa[((size_t)(b * S_ + srow) * H_ + h) * DK_ + ni * 16 + l16] =
          f2bf(o[ni][r] * linv);
  }
}

// ---------------------------------------------------------------------------
// Final output GEMM: fp32 row-major C = A(bf16) @ Wo(bf16)^T.
// 128x64 tile -> grid 512 = 2 blocks/CU so one block's MFMA overlaps the
// other's barrier/vmcnt drain (R4's 128x128 ran 1 block/CU, fully exposed).
// ---------------------------------------------------------------------------
__global__ __launch_bounds__(256)
void gemm_out(const unsigned short* __restrict__ A, const unsigned short* __restrict__ W,
              float* __restrict__ out) {
  __shared__ unsigned short As[2][128 * 32];
  __shared__ unsigned short Bs[2][64 * 32];
  const int t = threadIdx.x, lane = t & 63, wave = t >> 6;
  const int l16 = lane & 15, quad = lane >> 4;
  const int wm = wave >> 1, wn = wave & 1;
  const int m0 = blockIdx.y * 128, j0 = blockIdx.x * 64;

  f32x4 acc[4][2];
#pragma unroll
  for (int i = 0; i < 4; ++i)
#pragma unroll
    for (int j = 0; j < 2; ++j) acc[i][j] = (f32x4)(0.0f);

  auto stage = [&](int kb, int buf) {
#pragma unroll
    for (int i = 0; i < 2; ++i) {
      const int c  = (wave * 2 + i) * 64 + lane;   // A chunks 0..511
      const int r  = c >> 2;
      const int co = (c & 3) * 8;
      gl_lds16(&A[(size_t)(m0 + r) * D_ + kb + co], &As[buf][(wave * 2 + i) * 512]);
    }
    {
      const int c  = wave * 64 + lane;             // B chunks 0..255
      const int r  = c >> 2;
      const int co = (c & 3) * 8;
      gl_lds16(&W[(size_t)(j0 + r) * D_ + kb + co], &Bs[buf][wave * 512]);
    }
  };

  stage(0, 0);
  for (int kb = 0; kb < D_; kb += 32) {
    const int buf = (kb >> 5) & 1;
    __syncthreads();
    if (kb + 32 < D_) stage(kb + 32, buf ^ 1);

    bf16x8 af[4], bfr[2];
#pragma unroll
    for (int mi = 0; mi < 4; ++mi)
      af[mi] = *(const bf16x8*)&As[buf][(wm * 64 + mi * 16 + l16) * 32 + quad * 8];
#pragma unroll
    for (int ni = 0; ni < 2; ++ni)
      bfr[ni] = *(const bf16x8*)&Bs[buf][(wn * 32 + ni * 16 + l16) * 32 + quad * 8];
#pragma unroll
    for (int mi = 0; mi < 4; ++mi)
#pragma unroll
      for (int ni = 0; ni < 2; ++ni)
        acc[mi][ni] = MFMA_BF16(af[mi], bfr[ni], acc[mi][ni]);
  }

#pragma unroll
  for (int mi = 0; mi < 4; ++mi) {
    const int rowb = m0 + wm * 64 + mi * 16 + quad * 4;
#pragma unroll
    for (int ni = 0; ni < 2; ++ni) {
      const int col = j0 + wn * 32 + ni * 16 + l16;
#pragma unroll
      for (int r = 0; r < 4; ++r)
        out[(size_t)(rowb + r) * D_ + col] = acc[mi][ni][r];
    }
  }
}

// ---------------------------------------------------------------------------
extern "C" void kernel_launch(void* const* d_in, const int* in_sizes, int n_in,
                              void* d_out, int out_size, void* d_ws, size_t ws_size,
                              hipStream_t stream) {
  (void)in_sizes; (void)n_in; (void)out_size; (void)ws_size;
  const float* q  = (const float*)d_in[0];
  const float* k  = (const float*)d_in[1];
  const float* v  = (const float*)d_in[2];
  const float* Wq = (const float*)d_in[3];
  const float* Wk = (const float*)d_in[4];
  const float* Wv = (const float*)d_in[5];
  const float* Wo = (const float*)d_in[6];
  const float* qw = (const float*)d_in[7];
  const float* kw = (const float*)d_in[8];

  char* ws = (char*)d_ws;
  const size_t MB = 1u << 20;
  unsigned short* qb  = (unsigned short*)(ws + 0 * MB);    // bf16 inputs
  unsigned short* kb  = (unsigned short*)(ws + 8 * MB);
  unsigned short* vb  = (unsigned short*)(ws + 16 * MB);
  unsigned short* wqb = (unsigned short*)(ws + 24 * MB);
  unsigned short* wkb = (unsigned short*)(ws + 26 * MB);
  unsigned short* wvb = (unsigned short*)(ws + 28 * MB);
  unsigned short* wob = (unsigned short*)(ws + 30 * MB);
  unsigned short* Qb  = (unsigned short*)(ws + 32 * MB);   // normed+roped Q (scaled)
  unsigned short* Kb  = (unsigned short*)(ws + 40 * MB);   // normed+roped K
  unsigned short* Vtb = (unsigned short*)(ws + 48 * MB);   // V^T [bh][dk][s]
  unsigned short* Ab  = (unsigned short*)(ws + 56 * MB);   // attn out row-major

  cvt_bf16<<<dim3(4096, 7), 256, 0, stream>>>(q, k, v, Wq, Wk, Wv, Wo,
                                              qb, kb, vb, wqb, wkb, wvb, wob);

  gemm_qkv<<<dim3(D_ / 128, (B_ * S_) / 128, 3), 256, 0, stream>>>(
      qb, kb, vb, wqb, wkb, wvb, Qb, Kb, Vtb, qw, kw);

  flash4<<<1024, 256, 0, stream>>>(Qb, Kb, Vtb, Ab);

  gemm_out<<<dim3(D_ / 64, (B_ * S_) / 128), 256, 0, stream>>>(Ab, wob, (float*)d_out);
}